// Round 1
// baseline (8533.360 us; speedup 1.0000x reference)
//
#include <hip/hip_runtime.h>

#define FIN 128
#define HD 128
#define COUT 16

// ---------- helpers ----------
__device__ __forceinline__ unsigned fenc(float f) {
    unsigned u = __float_as_uint(f);
    return (u & 0x80000000u) ? ~u : (u | 0x80000000u);
}
__device__ __forceinline__ float fdec(unsigned u) {
    return (u & 0x80000000u) ? __uint_as_float(u ^ 0x80000000u)
                             : __uint_as_float(~u);
}
__device__ __forceinline__ float lrelu02(float x) { return x > 0.f ? x : 0.2f * x; }

__device__ __forceinline__ void atomAddF(float* p, float v) {
    unsafeAtomicAdd(p, v);   // hw global_atomic_add_f32 on gfx950
}

// ---------- degree / norm ----------
__global__ void k_init_deg(float* deg, int n) {
    int i = blockIdx.x * 256 + threadIdx.x;
    if (i < n) deg[i] = 1.0f;   // self-loop weight
}
__global__ void k_accum_deg(const int* __restrict__ dst, const float* __restrict__ ew,
                            float* deg, int e) {
    int i = blockIdx.x * 256 + threadIdx.x;
    if (i < e) atomAddF(&deg[dst[i]], ew[i]);
}
__global__ void k_dinv(float* deg, int n) {
    int i = blockIdx.x * 256 + threadIdx.x;
    if (i < n) deg[i] = rsqrtf(deg[i]);   // deg >= 1 always (self loop)
}
__global__ void k_norm(const int* __restrict__ src, const int* __restrict__ dst,
                       const float* __restrict__ ew, const float* __restrict__ dinv,
                       float* norm, int e) {
    int i = blockIdx.x * 256 + threadIdx.x;
    if (i < e) norm[i] = dinv[src[i]] * ew[i] * dinv[dst[i]];
}

// ---------- GEMM: [M,128] @ [128,128], M % 32 == 0 ----------
__launch_bounds__(256)
__global__ void k_gemm128(const float* __restrict__ A, const float* __restrict__ W,
                          float* __restrict__ Out) {
    __shared__ float Ws[64 * 128];   // K-chunk of W: 32 KB
    __shared__ float As[32 * 128];   // A tile: 16 KB
    int tid = threadIdx.x;
    int rowBase = blockIdx.x * 32;

    const float4* Av = (const float4*)(A + (size_t)rowBase * 128);
    float4* Asv = (float4*)As;
#pragma unroll
    for (int i = 0; i < 4; i++) Asv[i * 256 + tid] = Av[i * 256 + tid];

    int col = (tid & 31) * 4;
    int row = (tid >> 5) * 4;
    float acc[4][4] = {};

    for (int kc = 0; kc < 2; kc++) {
        __syncthreads();
        const float4* Wv = (const float4*)(W + kc * 64 * 128);
        float4* Wsv = (float4*)Ws;
#pragma unroll
        for (int i = 0; i < 8; i++) Wsv[i * 256 + tid] = Wv[i * 256 + tid];
        __syncthreads();
#pragma unroll 8
        for (int kk = 0; kk < 64; kk++) {
            int k = kc * 64 + kk;
            float4 b = *(const float4*)&Ws[kk * 128 + col];
            float a0 = As[(row + 0) * 128 + k];
            float a1 = As[(row + 1) * 128 + k];
            float a2 = As[(row + 2) * 128 + k];
            float a3 = As[(row + 3) * 128 + k];
            acc[0][0] = fmaf(a0, b.x, acc[0][0]);
            acc[0][1] = fmaf(a0, b.y, acc[0][1]);
            acc[0][2] = fmaf(a0, b.z, acc[0][2]);
            acc[0][3] = fmaf(a0, b.w, acc[0][3]);
            acc[1][0] = fmaf(a1, b.x, acc[1][0]);
            acc[1][1] = fmaf(a1, b.y, acc[1][1]);
            acc[1][2] = fmaf(a1, b.z, acc[1][2]);
            acc[1][3] = fmaf(a1, b.w, acc[1][3]);
            acc[2][0] = fmaf(a2, b.x, acc[2][0]);
            acc[2][1] = fmaf(a2, b.y, acc[2][1]);
            acc[2][2] = fmaf(a2, b.z, acc[2][2]);
            acc[2][3] = fmaf(a2, b.w, acc[2][3]);
            acc[3][0] = fmaf(a3, b.x, acc[3][0]);
            acc[3][1] = fmaf(a3, b.y, acc[3][1]);
            acc[3][2] = fmaf(a3, b.z, acc[3][2]);
            acc[3][3] = fmaf(a3, b.w, acc[3][3]);
        }
    }
#pragma unroll
    for (int i = 0; i < 4; i++) {
        float4 o;
        o.x = acc[i][0]; o.y = acc[i][1]; o.z = acc[i][2]; o.w = acc[i][3];
        *(float4*)&Out[(size_t)(rowBase + row + i) * 128 + col] = o;
    }
}

// ---------- GCN aggregation ----------
// agg[i] = t[i] * dinv[i]^2   (self loop contribution)
__global__ void k_gcn_self(const float* __restrict__ t, const float* __restrict__ dinv,
                           float* __restrict__ agg, int n) {
    int idx = blockIdx.x * 256 + threadIdx.x;
    int i = idx >> 5, f = idx & 31;
    if (i >= n) return;
    float d = dinv[i];
    float s = d * d;
    float4 v = ((const float4*)t)[(size_t)i * 32 + f];
    v.x *= s; v.y *= s; v.z *= s; v.w *= s;
    ((float4*)agg)[(size_t)i * 32 + f] = v;
}
// agg[dst] += t[src] * norm[e], 32 threads (float4 lanes) per edge
__global__ void k_gcn_scatter(const int* __restrict__ src, const int* __restrict__ dst,
                              const float* __restrict__ norm, const float* __restrict__ t,
                              float* __restrict__ agg, int e) {
    int idx = blockIdx.x * 256 + threadIdx.x;
    int ei = idx >> 5;
    if (ei >= e) return;
    int lane = idx & 31;
    int s = src[ei], d = dst[ei];
    float w = norm[ei];
    float4 v = ((const float4*)t)[(size_t)s * 32 + lane];
    float* p = &agg[(size_t)d * 128 + lane * 4];
    atomAddF(p + 0, v.x * w);
    atomAddF(p + 1, v.y * w);
    atomAddF(p + 2, v.z * w);
    atomAddF(p + 3, v.w * w);
}
// out = relu(agg + b)
__global__ void k_relu_bias(const float* __restrict__ agg, const float* __restrict__ b,
                            float* __restrict__ out, int n) {
    int idx = blockIdx.x * 256 + threadIdx.x;
    int i = idx >> 5, f = idx & 31;
    if (i >= n) return;
    float4 v = ((const float4*)agg)[(size_t)i * 32 + f];
    float4 bb = ((const float4*)b)[f];
    v.x = fmaxf(v.x + bb.x, 0.f);
    v.y = fmaxf(v.y + bb.y, 0.f);
    v.z = fmaxf(v.z + bb.z, 0.f);
    v.w = fmaxf(v.w + bb.w, 0.f);
    ((float4*)out)[(size_t)i * 32 + f] = v;
}

// ---------- GAT ----------
// one wave per node: as = g.att_src, ad = g.att_dst; amax init with self-loop logit
__global__ void k_attn_node(const float* __restrict__ g, const float* __restrict__ att_src,
                            const float* __restrict__ att_dst, float* __restrict__ as_,
                            float* __restrict__ ad_, unsigned* __restrict__ amax, int n) {
    int node = blockIdx.x * 4 + (threadIdx.x >> 6);
    int lane = threadIdx.x & 63;
    if (node >= n) return;
    float g0 = g[(size_t)node * 128 + lane];
    float g1 = g[(size_t)node * 128 + 64 + lane];
    float s = g0 * att_src[lane] + g1 * att_src[64 + lane];
    float d = g0 * att_dst[lane] + g1 * att_dst[64 + lane];
#pragma unroll
    for (int m = 32; m >= 1; m >>= 1) {
        s += __shfl_xor(s, m, 64);
        d += __shfl_xor(d, m, 64);
    }
    if (lane == 0) {
        as_[node] = s;
        ad_[node] = d;
        amax[node] = fenc(lrelu02(s + d));
    }
}
__global__ void k_attn_edge_max(const int* __restrict__ src, const int* __restrict__ dst,
                                const float* __restrict__ as_, const float* __restrict__ ad_,
                                float* __restrict__ abuf, unsigned* __restrict__ amax, int e) {
    int i = blockIdx.x * 256 + threadIdx.x;
    if (i >= e) return;
    float a = lrelu02(as_[src[i]] + ad_[dst[i]]);
    abuf[i] = a;
    atomicMax(&amax[dst[i]], fenc(a));
}
__global__ void k_denom_init(const float* __restrict__ as_, const float* __restrict__ ad_,
                             const unsigned* __restrict__ amax, float* __restrict__ denom, int n) {
    int i = blockIdx.x * 256 + threadIdx.x;
    if (i >= n) return;
    float a = lrelu02(as_[i] + ad_[i]);
    denom[i] = expf(a - fdec(amax[i]));
}
__global__ void k_denom_edge(const int* __restrict__ dst, const unsigned* __restrict__ amax,
                             float* __restrict__ abuf, float* __restrict__ denom, int e) {
    int i = blockIdx.x * 256 + threadIdx.x;
    if (i >= e) return;
    int d = dst[i];
    float ex = expf(abuf[i] - fdec(amax[d]));
    abuf[i] = ex;
    atomAddF(&denom[d], ex);
}
// agg[i] = g[i] * alpha_self
__global__ void k_gat_self(const float* __restrict__ g, const float* __restrict__ as_,
                           const float* __restrict__ ad_, const unsigned* __restrict__ amax,
                           const float* __restrict__ denom, float* __restrict__ agg, int n) {
    int idx = blockIdx.x * 256 + threadIdx.x;
    int i = idx >> 5, f = idx & 31;
    if (i >= n) return;
    float a = lrelu02(as_[i] + ad_[i]);
    float alpha = expf(a - fdec(amax[i])) / denom[i];
    float4 v = ((const float4*)g)[(size_t)i * 32 + f];
    v.x *= alpha; v.y *= alpha; v.z *= alpha; v.w *= alpha;
    ((float4*)agg)[(size_t)i * 32 + f] = v;
}
__global__ void k_gat_scatter(const int* __restrict__ src, const int* __restrict__ dst,
                              const float* __restrict__ abuf, const float* __restrict__ denom,
                              const float* __restrict__ g, float* __restrict__ agg, int e) {
    int idx = blockIdx.x * 256 + threadIdx.x;
    int ei = idx >> 5;
    if (ei >= e) return;
    int lane = idx & 31;
    int s = src[ei], d = dst[ei];
    float alpha = abuf[ei] / denom[d];
    float4 v = ((const float4*)g)[(size_t)s * 32 + lane];
    float* p = &agg[(size_t)d * 128 + lane * 4];
    atomAddF(p + 0, v.x * alpha);
    atomAddF(p + 1, v.y * alpha);
    atomAddF(p + 2, v.z * alpha);
    atomAddF(p + 3, v.w * alpha);
}

// ---------- final: out = relu(agg + bg) @ Wc + bc ----------
__launch_bounds__(256)
__global__ void k_final(const float* __restrict__ agg, const float* __restrict__ bg,
                        const float* __restrict__ Wc, const float* __restrict__ bc,
                        float* __restrict__ out, int n) {
    __shared__ float Wcs[128 * 16];
    __shared__ float bgs[128];
    __shared__ float bcs[16];
    int tid = threadIdx.x;
    for (int i = tid; i < 128 * 16; i += 256) Wcs[i] = Wc[i];
    if (tid < 128) bgs[tid] = bg[tid];
    if (tid < 16) bcs[tid] = bc[tid];
    __syncthreads();
    int node = blockIdx.x * 16 + (tid >> 4);
    int col = tid & 15;
    if (node >= n) return;
    float acc = 0.f;
#pragma unroll 4
    for (int k4 = 0; k4 < 32; k4++) {
        float4 a = ((const float4*)agg)[(size_t)node * 32 + k4];
        float4 bb = ((const float4*)bgs)[k4];
        a.x = fmaxf(a.x + bb.x, 0.f);
        a.y = fmaxf(a.y + bb.y, 0.f);
        a.z = fmaxf(a.z + bb.z, 0.f);
        a.w = fmaxf(a.w + bb.w, 0.f);
        acc = fmaf(a.x, Wcs[(k4 * 4 + 0) * 16 + col], acc);
        acc = fmaf(a.y, Wcs[(k4 * 4 + 1) * 16 + col], acc);
        acc = fmaf(a.z, Wcs[(k4 * 4 + 2) * 16 + col], acc);
        acc = fmaf(a.w, Wcs[(k4 * 4 + 3) * 16 + col], acc);
    }
    out[(size_t)node * 16 + col] = acc + bcs[col];
}

// ---------- launch ----------
extern "C" void kernel_launch(void* const* d_in, const int* in_sizes, int n_in,
                              void* d_out, int out_size, void* d_ws, size_t ws_size,
                              hipStream_t stream) {
    const float* x      = (const float*)d_in[0];
    const int*   eidx   = (const int*)d_in[1];
    const float* ew     = (const float*)d_in[2];
    const float* W1     = (const float*)d_in[3];
    const float* b1     = (const float*)d_in[4];
    const float* W2     = (const float*)d_in[5];
    const float* b2     = (const float*)d_in[6];
    const float* Wg     = (const float*)d_in[7];
    const float* attS   = (const float*)d_in[8];
    const float* attD   = (const float*)d_in[9];
    const float* bg     = (const float*)d_in[10];
    const float* Wc     = (const float*)d_in[11];
    const float* bc     = (const float*)d_in[12];

    const int N = in_sizes[0] / FIN;   // 100000
    const int E = in_sizes[2];         // 1600000
    const int* src = eidx;
    const int* dst = eidx + E;

    float* ws = (float*)d_ws;
    float* dinv  = ws;                 // N
    float* norm  = dinv + N;           // E
    float* abuf  = norm + E;           // E
    float* as_   = abuf + E;           // N
    float* ad_   = as_ + N;            // N
    unsigned* amax = (unsigned*)(ad_ + N);   // N
    float* denom = (float*)(amax + N); // N
    float* buf0  = denom + N;          // N*128
    float* buf1  = buf0 + (size_t)N * 128;   // N*128

    const int B = 256;
    dim3 blk(B);

    // norm precompute
    k_init_deg<<<(N + B - 1) / B, blk, 0, stream>>>(dinv, N);
    k_accum_deg<<<(E + B - 1) / B, blk, 0, stream>>>(dst, ew, dinv, E);
    k_dinv<<<(N + B - 1) / B, blk, 0, stream>>>(dinv, N);
    k_norm<<<(E + B - 1) / B, blk, 0, stream>>>(src, dst, ew, dinv, norm, E);

    int gemmGrid = N / 32;                 // N % 32 == 0
    int nodeVec  = (N * 32 + B - 1) / B;   // n*32 threads (float4 lanes)
    int edgeVec  = ((size_t)E * 32 + B - 1) / B;

    // GCN layer 1: h1 = relu(agg(x@W1) + b1)
    k_gemm128<<<gemmGrid, blk, 0, stream>>>(x, W1, buf0);
    k_gcn_self<<<nodeVec, blk, 0, stream>>>(buf0, dinv, buf1, N);
    k_gcn_scatter<<<edgeVec, blk, 0, stream>>>(src, dst, norm, buf0, buf1, E);
    k_relu_bias<<<nodeVec, blk, 0, stream>>>(buf1, b1, buf0, N);   // h1 -> buf0

    // GCN layer 2
    k_gemm128<<<gemmGrid, blk, 0, stream>>>(buf0, W2, buf1);
    k_gcn_self<<<nodeVec, blk, 0, stream>>>(buf1, dinv, buf0, N);
    k_gcn_scatter<<<edgeVec, blk, 0, stream>>>(src, dst, norm, buf1, buf0, E);
    k_relu_bias<<<nodeVec, blk, 0, stream>>>(buf0, b2, buf1, N);   // h2 -> buf1

    // GAT
    k_gemm128<<<gemmGrid, blk, 0, stream>>>(buf1, Wg, buf0);       // g -> buf0
    k_attn_node<<<(N + 3) / 4, blk, 0, stream>>>(buf0, attS, attD, as_, ad_, amax, N);
    k_attn_edge_max<<<(E + B - 1) / B, blk, 0, stream>>>(src, dst, as_, ad_, abuf, amax, E);
    k_denom_init<<<(N + B - 1) / B, blk, 0, stream>>>(as_, ad_, amax, denom, N);
    k_denom_edge<<<(E + B - 1) / B, blk, 0, stream>>>(dst, amax, abuf, denom, E);
    k_gat_self<<<nodeVec, blk, 0, stream>>>(buf0, as_, ad_, amax, denom, buf1, N);
    k_gat_scatter<<<edgeVec, blk, 0, stream>>>(src, dst, abuf, denom, buf0, buf1, E);

    // final projection
    k_final<<<(N + 15) / 16, blk, 0, stream>>>(buf1, bg, Wc, bc, (float*)d_out, N);
}

// Round 2
// 1291.602 us; speedup vs baseline: 6.6068x; 6.6068x over previous
//
#include <hip/hip_runtime.h>

#define FIN 128
#define HD 128
#define COUT 16

// ---------- helpers ----------
__device__ __forceinline__ float lrelu02(float x) { return x > 0.f ? x : 0.2f * x; }
__device__ __forceinline__ void atomAddF(float* p, float v) {
    unsafeAtomicAdd(p, v);   // hw global_atomic_add_f32 on gfx950
}

// ---------- CSR build ----------
__global__ void k_init(int* rowcnt, float* wdeg, int n) {
    int i = blockIdx.x * 256 + threadIdx.x;
    if (i < n) { rowcnt[i] = 0; wdeg[i] = 1.0f; }   // self-loop weight 1
}
__global__ void k_hist(const int* __restrict__ dst, const float* __restrict__ ew,
                       int* rowcnt, float* wdeg, int e) {
    int i = blockIdx.x * 256 + threadIdx.x;
    if (i < e) {
        atomicAdd(&rowcnt[dst[i]], 1);
        atomAddF(&wdeg[dst[i]], ew[i]);
    }
}
__global__ void k_dinv(float* wdeg, int n) {
    int i = blockIdx.x * 256 + threadIdx.x;
    if (i < n) wdeg[i] = rsqrtf(wdeg[i]);   // deg >= 1 (self loop)
}
// single block, 1024 threads: exclusive scan of rowcnt -> rowptr, init cursor.
// SAFE when cursor aliases rowcnt: count is read into a local before overwrite.
__global__ __launch_bounds__(1024)
void k_scan(const int* __restrict__ rowcnt, int* __restrict__ rowptr,
            int* __restrict__ cursor, int n) {
    __shared__ int part[1024];
    int tid = threadIdx.x;
    int chunk = (n + 1023) / 1024;
    int begin = tid * chunk;
    int end = begin + chunk; if (end > n) end = n; if (begin > n) begin = n;
    int s = 0;
    for (int i = begin; i < end; i++) s += rowcnt[i];
    part[tid] = s;
    __syncthreads();
    for (int off = 1; off < 1024; off <<= 1) {
        int t = (tid >= off) ? part[tid - off] : 0;
        __syncthreads();
        part[tid] += t;
        __syncthreads();
    }
    int run = (tid == 0) ? 0 : part[tid - 1];
    for (int i = begin; i < end; i++) {
        int c = rowcnt[i];          // read BEFORE overwrite (cursor may alias)
        rowptr[i] = run;
        cursor[i] = run;
        run += c;
    }
    if (tid == 1023) rowptr[n] = part[1023];
}
__global__ void k_fill(const int* __restrict__ src, const int* __restrict__ dst,
                       const float* __restrict__ ew, const float* __restrict__ dinv,
                       int* __restrict__ cursor, int* __restrict__ csr_src,
                       float* __restrict__ csr_w, int e) {
    int i = blockIdx.x * 256 + threadIdx.x;
    if (i >= e) return;
    int s = src[i], d = dst[i];
    int pos = atomicAdd(&cursor[d], 1);
    csr_src[pos] = s;
    csr_w[pos] = dinv[s] * ew[i] * dinv[d];
}

// ---------- GEMM: [M,128] @ [128,128], M % 32 == 0 ----------
__launch_bounds__(256)
__global__ void k_gemm128(const float* __restrict__ A, const float* __restrict__ W,
                          float* __restrict__ Out) {
    __shared__ float Ws[64 * 128];
    __shared__ float As[32 * 128];
    int tid = threadIdx.x;
    int rowBase = blockIdx.x * 32;

    const float4* Av = (const float4*)(A + (size_t)rowBase * 128);
    float4* Asv = (float4*)As;
#pragma unroll
    for (int i = 0; i < 4; i++) Asv[i * 256 + tid] = Av[i * 256 + tid];

    int col = (tid & 31) * 4;
    int row = (tid >> 5) * 4;
    float acc[4][4] = {};

    for (int kc = 0; kc < 2; kc++) {
        __syncthreads();
        const float4* Wv = (const float4*)(W + kc * 64 * 128);
        float4* Wsv = (float4*)Ws;
#pragma unroll
        for (int i = 0; i < 8; i++) Wsv[i * 256 + tid] = Wv[i * 256 + tid];
        __syncthreads();
#pragma unroll 8
        for (int kk = 0; kk < 64; kk++) {
            int k = kc * 64 + kk;
            float4 b = *(const float4*)&Ws[kk * 128 + col];
            float a0 = As[(row + 0) * 128 + k];
            float a1 = As[(row + 1) * 128 + k];
            float a2 = As[(row + 2) * 128 + k];
            float a3 = As[(row + 3) * 128 + k];
            acc[0][0] = fmaf(a0, b.x, acc[0][0]);
            acc[0][1] = fmaf(a0, b.y, acc[0][1]);
            acc[0][2] = fmaf(a0, b.z, acc[0][2]);
            acc[0][3] = fmaf(a0, b.w, acc[0][3]);
            acc[1][0] = fmaf(a1, b.x, acc[1][0]);
            acc[1][1] = fmaf(a1, b.y, acc[1][1]);
            acc[1][2] = fmaf(a1, b.z, acc[1][2]);
            acc[1][3] = fmaf(a1, b.w, acc[1][3]);
            acc[2][0] = fmaf(a2, b.x, acc[2][0]);
            acc[2][1] = fmaf(a2, b.y, acc[2][1]);
            acc[2][2] = fmaf(a2, b.z, acc[2][2]);
            acc[2][3] = fmaf(a2, b.w, acc[2][3]);
            acc[3][0] = fmaf(a3, b.x, acc[3][0]);
            acc[3][1] = fmaf(a3, b.y, acc[3][1]);
            acc[3][2] = fmaf(a3, b.z, acc[3][2]);
            acc[3][3] = fmaf(a3, b.w, acc[3][3]);
        }
    }
#pragma unroll
    for (int i = 0; i < 4; i++) {
        float4 o;
        o.x = acc[i][0]; o.y = acc[i][1]; o.z = acc[i][2]; o.w = acc[i][3];
        *(float4*)&Out[(size_t)(rowBase + row + i) * 128 + col] = o;
    }
}

// ---------- GCN gather: one wave per node ----------
__launch_bounds__(256)
__global__ void k_gcn_gather(const int* __restrict__ rowptr, const int* __restrict__ csr_src,
                             const float* __restrict__ csr_w, const float* __restrict__ t,
                             const float* __restrict__ dinv, const float* __restrict__ b,
                             float* __restrict__ out, int n) {
    int node = blockIdx.x * 4 + (threadIdx.x >> 6);
    int lane = threadIdx.x & 63;
    if (node >= n) return;
    const float2* tv = (const float2*)t;
    float d = dinv[node];
    float sw = d * d;
    float2 acc = tv[(size_t)node * 64 + lane];
    acc.x *= sw; acc.y *= sw;
    int r0 = rowptr[node], r1 = rowptr[node + 1];
    for (int e = r0; e < r1; e++) {
        int s = csr_src[e];
        float w = csr_w[e];
        float2 v = tv[(size_t)s * 64 + lane];
        acc.x = fmaf(v.x, w, acc.x);
        acc.y = fmaf(v.y, w, acc.y);
    }
    float2 bb = ((const float2*)b)[lane];
    acc.x = fmaxf(acc.x + bb.x, 0.f);
    acc.y = fmaxf(acc.y + bb.y, 0.f);
    ((float2*)out)[(size_t)node * 64 + lane] = acc;
}

// ---------- GAT ----------
__global__ void k_attn_node(const float* __restrict__ g, const float* __restrict__ att_src,
                            const float* __restrict__ att_dst, float* __restrict__ as_,
                            float* __restrict__ ad_, int n) {
    int node = blockIdx.x * 4 + (threadIdx.x >> 6);
    int lane = threadIdx.x & 63;
    if (node >= n) return;
    float g0 = g[(size_t)node * 128 + lane];
    float g1 = g[(size_t)node * 128 + 64 + lane];
    float s = g0 * att_src[lane] + g1 * att_src[64 + lane];
    float d = g0 * att_dst[lane] + g1 * att_dst[64 + lane];
#pragma unroll
    for (int m = 32; m >= 1; m >>= 1) {
        s += __shfl_xor(s, m, 64);
        d += __shfl_xor(d, m, 64);
    }
    if (lane == 0) {
        as_[node] = s;
        ad_[node] = d;
    }
}
// full edge-softmax + aggregation per node, one wave per node; fuses +bg and relu
__launch_bounds__(256)
__global__ void k_gat_gather(const int* __restrict__ rowptr, const int* __restrict__ csr_src,
                             const float* __restrict__ g, const float* __restrict__ as_,
                             const float* __restrict__ ad_, const float* __restrict__ bg,
                             float* __restrict__ out, int n) {
    int node = blockIdx.x * 4 + (threadIdx.x >> 6);
    int lane = threadIdx.x & 63;
    if (node >= n) return;
    int r0 = rowptr[node], r1 = rowptr[node + 1];
    float ad_d = ad_[node];
    float self_logit = lrelu02(as_[node] + ad_d);
    float m = self_logit;
    for (int e = r0 + lane; e < r1; e += 64)
        m = fmaxf(m, lrelu02(as_[csr_src[e]] + ad_d));
#pragma unroll
    for (int k = 32; k >= 1; k >>= 1)
        m = fmaxf(m, __shfl_xor(m, k, 64));
    const float2* gv = (const float2*)g;
    float ex = __expf(self_logit - m);
    float den = ex;
    float2 v = gv[(size_t)node * 64 + lane];
    float2 acc; acc.x = ex * v.x; acc.y = ex * v.y;
    for (int e = r0; e < r1; e++) {
        int s = csr_src[e];
        float a = lrelu02(as_[s] + ad_d);
        float w = __expf(a - m);
        den += w;
        float2 u = gv[(size_t)s * 64 + lane];
        acc.x = fmaf(u.x, w, acc.x);
        acc.y = fmaf(u.y, w, acc.y);
    }
    float inv = 1.0f / den;
    float2 bb = ((const float2*)bg)[lane];
    acc.x = fmaxf(acc.x * inv + bb.x, 0.f);
    acc.y = fmaxf(acc.y * inv + bb.y, 0.f);
    ((float2*)out)[(size_t)node * 64 + lane] = acc;
}

// ---------- final: out = agg @ Wc + bc (agg already relu'd) ----------
__launch_bounds__(256)
__global__ void k_final(const float* __restrict__ agg, const float* __restrict__ Wc,
                        const float* __restrict__ bc, float* __restrict__ out, int n) {
    __shared__ float Wcs[128 * 16];
    __shared__ float bcs[16];
    int tid = threadIdx.x;
    for (int i = tid; i < 128 * 16; i += 256) Wcs[i] = Wc[i];
    if (tid < 16) bcs[tid] = bc[tid];
    __syncthreads();
    int node = blockIdx.x * 16 + (tid >> 4);
    int col = tid & 15;
    if (node >= n) return;
    float acc = 0.f;
#pragma unroll 8
    for (int k4 = 0; k4 < 32; k4++) {
        float4 a = ((const float4*)agg)[(size_t)node * 32 + k4];
        acc = fmaf(a.x, Wcs[(k4 * 4 + 0) * 16 + col], acc);
        acc = fmaf(a.y, Wcs[(k4 * 4 + 1) * 16 + col], acc);
        acc = fmaf(a.z, Wcs[(k4 * 4 + 2) * 16 + col], acc);
        acc = fmaf(a.w, Wcs[(k4 * 4 + 3) * 16 + col], acc);
    }
    out[(size_t)node * 16 + col] = acc + bcs[col];
}

// ---------- launch ----------
extern "C" void kernel_launch(void* const* d_in, const int* in_sizes, int n_in,
                              void* d_out, int out_size, void* d_ws, size_t ws_size,
                              hipStream_t stream) {
    const float* x      = (const float*)d_in[0];
    const int*   eidx   = (const int*)d_in[1];
    const float* ew     = (const float*)d_in[2];
    const float* W1     = (const float*)d_in[3];
    const float* b1     = (const float*)d_in[4];
    const float* W2     = (const float*)d_in[5];
    const float* b2     = (const float*)d_in[6];
    const float* Wg     = (const float*)d_in[7];
    const float* attS   = (const float*)d_in[8];
    const float* attD   = (const float*)d_in[9];
    const float* bg     = (const float*)d_in[10];
    const float* Wc     = (const float*)d_in[11];
    const float* bc     = (const float*)d_in[12];

    const int N = in_sizes[0] / FIN;   // 100000
    const int E = in_sizes[2];         // 1600000
    const int* src = eidx;
    const int* dst = eidx + E;

    char* p = (char*)d_ws;
    int*   rowptr  = (int*)p;                 p += (size_t)(N + 1) * 4;
    int*   rowcnt  = (int*)p;                 p += (size_t)N * 4;   // reused as cursor
    int*   csr_src = (int*)p;                 p += (size_t)E * 4;
    float* csr_w   = (float*)p;               p += (size_t)E * 4;
    float* dinv    = (float*)p;               p += (size_t)N * 4;
    float* as_     = (float*)p;               p += (size_t)N * 4;
    float* ad_     = (float*)p;               p += (size_t)N * 4;
    float* buf0    = (float*)p;               p += (size_t)N * 128 * 4;
    float* buf1    = (float*)p;

    const int B = 256;
    dim3 blk(B);
    int nGrid = (N + B - 1) / B;
    int eGrid = (E + B - 1) / B;
    int waveGrid = (N + 3) / 4;
    int gemmGrid = N / 32;

    k_init<<<nGrid, blk, 0, stream>>>(rowcnt, dinv, N);
    k_hist<<<eGrid, blk, 0, stream>>>(dst, ew, rowcnt, dinv, E);
    k_dinv<<<nGrid, blk, 0, stream>>>(dinv, N);
    k_scan<<<1, 1024, 0, stream>>>(rowcnt, rowptr, rowcnt, N);
    k_fill<<<eGrid, blk, 0, stream>>>(src, dst, ew, dinv, rowcnt, csr_src, csr_w, E);

    k_gemm128<<<gemmGrid, blk, 0, stream>>>(x, W1, buf0);
    k_gcn_gather<<<waveGrid, blk, 0, stream>>>(rowptr, csr_src, csr_w, buf0, dinv, b1, buf1, N);
    k_gemm128<<<gemmGrid, blk, 0, stream>>>(buf1, W2, buf0);
    k_gcn_gather<<<waveGrid, blk, 0, stream>>>(rowptr, csr_src, csr_w, buf0, dinv, b2, buf1, N);
    k_gemm128<<<gemmGrid, blk, 0, stream>>>(buf1, Wg, buf0);
    k_attn_node<<<waveGrid, blk, 0, stream>>>(buf0, attS, attD, as_, ad_, N);
    k_gat_gather<<<waveGrid, blk, 0, stream>>>(rowptr, csr_src, buf0, as_, ad_, bg, buf1, N);
    k_final<<<(N + 15) / 16, blk, 0, stream>>>(buf1, Wc, bc, (float*)d_out, N);
}

// Round 3
// 1098.503 us; speedup vs baseline: 7.7682x; 1.1758x over previous
//
#include <hip/hip_runtime.h>

#define FIN 128
#define HD 128
#define COUT 16

#define SCAN_T 256
#define SCAN_ELEMS 8
#define SCAN_CHUNK (SCAN_T * SCAN_ELEMS)   // 2048 elements per block

// ---------- helpers ----------
__device__ __forceinline__ float lrelu02(float x) { return x > 0.f ? x : 0.2f * x; }
__device__ __forceinline__ void atomAddF(float* p, float v) {
    unsafeAtomicAdd(p, v);   // hw global_atomic_add_f32 on gfx950
}

// ---------- CSR build ----------
__global__ void k_init(int* rowcnt, float* wdeg, int n) {
    int i = blockIdx.x * 256 + threadIdx.x;
    if (i < n) { rowcnt[i] = 0; wdeg[i] = 1.0f; }   // self-loop weight 1
}
__global__ void k_hist(const int* __restrict__ dst, const float* __restrict__ ew,
                       int* rowcnt, float* wdeg, int e) {
    int i = blockIdx.x * 256 + threadIdx.x;
    if (i < e) {
        atomicAdd(&rowcnt[dst[i]], 1);
        atomAddF(&wdeg[dst[i]], ew[i]);
    }
}
__global__ void k_dinv(float* wdeg, int n) {
    int i = blockIdx.x * 256 + threadIdx.x;
    if (i < n) wdeg[i] = rsqrtf(wdeg[i]);   // deg >= 1 (self loop)
}

// ---------- two-level scan (replaces single-block k_scan) ----------
// phase 1: per-block sum of a 2048-element chunk (strided coalesced reads)
__global__ __launch_bounds__(SCAN_T)
void k_scan_partial(const int* __restrict__ rowcnt, int* __restrict__ blockSum, int n) {
    __shared__ int sh[SCAN_T];
    int t = threadIdx.x;
    int base = blockIdx.x * SCAN_CHUNK + t;
    int s = 0;
#pragma unroll
    for (int i = 0; i < SCAN_ELEMS; i++) {
        int idx = base + i * SCAN_T;
        if (idx < n) s += rowcnt[idx];
    }
    sh[t] = s;
    __syncthreads();
    for (int off = 128; off > 0; off >>= 1) {
        if (t < off) sh[t] += sh[t + off];
        __syncthreads();
    }
    if (t == 0) blockSum[blockIdx.x] = sh[0];
}
// phase 2: single small block scans the (<=256) block sums -> exclusive offsets,
// and writes rowptr[n] = total
__global__ __launch_bounds__(SCAN_T)
void k_scan_block(int* __restrict__ blockSum, int* __restrict__ rowptr,
                  int numBlocks, int n) {
    __shared__ int sh[SCAN_T];
    int t = threadIdx.x;
    int v = (t < numBlocks) ? blockSum[t] : 0;
    sh[t] = v;
    __syncthreads();
    for (int off = 1; off < SCAN_T; off <<= 1) {
        int tv = (t >= off) ? sh[t - off] : 0;
        __syncthreads();
        sh[t] += tv;
        __syncthreads();
    }
    // exclusive offset for block t
    int ex = (t == 0) ? 0 : sh[t - 1];
    if (t < numBlocks) blockSum[t] = ex;
    if (t == SCAN_T - 1) rowptr[n] = sh[SCAN_T - 1];
}
// phase 3: per-block local scan (contiguous 8 elems/thread) + block offset -> rowptr/cursor.
// cursor may alias rowcnt: all reads of this block's elements happen before writes
// within the owning thread.
__global__ __launch_bounds__(SCAN_T)
void k_scan_final(const int* __restrict__ rowcnt, const int* __restrict__ blockOff,
                  int* __restrict__ rowptr, int* __restrict__ cursor, int n) {
    __shared__ int sh[SCAN_T];
    int t = threadIdx.x;
    int base = blockIdx.x * SCAN_CHUNK + t * SCAN_ELEMS;
    int v[SCAN_ELEMS];
    int s = 0;
#pragma unroll
    for (int i = 0; i < SCAN_ELEMS; i++) {
        int idx = base + i;
        v[i] = (idx < n) ? rowcnt[idx] : 0;
        s += v[i];
    }
    sh[t] = s;
    __syncthreads();
    for (int off = 1; off < SCAN_T; off <<= 1) {
        int tv = (t >= off) ? sh[t - off] : 0;
        __syncthreads();
        sh[t] += tv;
        __syncthreads();
    }
    int run = blockOff[blockIdx.x] + ((t == 0) ? 0 : sh[t - 1]);
#pragma unroll
    for (int i = 0; i < SCAN_ELEMS; i++) {
        int idx = base + i;
        if (idx < n) { rowptr[idx] = run; cursor[idx] = run; }
        run += v[i];
    }
}

__global__ void k_fill(const int* __restrict__ src, const int* __restrict__ dst,
                       const float* __restrict__ ew, const float* __restrict__ dinv,
                       int* __restrict__ cursor, int* __restrict__ csr_src,
                       float* __restrict__ csr_w, int e) {
    int i = blockIdx.x * 256 + threadIdx.x;
    if (i >= e) return;
    int s = src[i], d = dst[i];
    int pos = atomicAdd(&cursor[d], 1);
    csr_src[pos] = s;
    csr_w[pos] = dinv[s] * ew[i] * dinv[d];
}

// ---------- GEMM: [M,128] @ [128,128], M % 32 == 0 ----------
__launch_bounds__(256)
__global__ void k_gemm128(const float* __restrict__ A, const float* __restrict__ W,
                          float* __restrict__ Out) {
    __shared__ float Ws[64 * 128];
    __shared__ float As[32 * 128];
    int tid = threadIdx.x;
    int rowBase = blockIdx.x * 32;

    const float4* Av = (const float4*)(A + (size_t)rowBase * 128);
    float4* Asv = (float4*)As;
#pragma unroll
    for (int i = 0; i < 4; i++) Asv[i * 256 + tid] = Av[i * 256 + tid];

    int col = (tid & 31) * 4;
    int row = (tid >> 5) * 4;
    float acc[4][4] = {};

    for (int kc = 0; kc < 2; kc++) {
        __syncthreads();
        const float4* Wv = (const float4*)(W + kc * 64 * 128);
        float4* Wsv = (float4*)Ws;
#pragma unroll
        for (int i = 0; i < 8; i++) Wsv[i * 256 + tid] = Wv[i * 256 + tid];
        __syncthreads();
#pragma unroll 8
        for (int kk = 0; kk < 64; kk++) {
            int k = kc * 64 + kk;
            float4 b = *(const float4*)&Ws[kk * 128 + col];
            float a0 = As[(row + 0) * 128 + k];
            float a1 = As[(row + 1) * 128 + k];
            float a2 = As[(row + 2) * 128 + k];
            float a3 = As[(row + 3) * 128 + k];
            acc[0][0] = fmaf(a0, b.x, acc[0][0]);
            acc[0][1] = fmaf(a0, b.y, acc[0][1]);
            acc[0][2] = fmaf(a0, b.z, acc[0][2]);
            acc[0][3] = fmaf(a0, b.w, acc[0][3]);
            acc[1][0] = fmaf(a1, b.x, acc[1][0]);
            acc[1][1] = fmaf(a1, b.y, acc[1][1]);
            acc[1][2] = fmaf(a1, b.z, acc[1][2]);
            acc[1][3] = fmaf(a1, b.w, acc[1][3]);
            acc[2][0] = fmaf(a2, b.x, acc[2][0]);
            acc[2][1] = fmaf(a2, b.y, acc[2][1]);
            acc[2][2] = fmaf(a2, b.z, acc[2][2]);
            acc[2][3] = fmaf(a2, b.w, acc[2][3]);
            acc[3][0] = fmaf(a3, b.x, acc[3][0]);
            acc[3][1] = fmaf(a3, b.y, acc[3][1]);
            acc[3][2] = fmaf(a3, b.z, acc[3][2]);
            acc[3][3] = fmaf(a3, b.w, acc[3][3]);
        }
    }
#pragma unroll
    for (int i = 0; i < 4; i++) {
        float4 o;
        o.x = acc[i][0]; o.y = acc[i][1]; o.z = acc[i][2]; o.w = acc[i][3];
        *(float4*)&Out[(size_t)(rowBase + row + i) * 128 + col] = o;
    }
}

// ---------- GCN gather: one wave per node ----------
__launch_bounds__(256)
__global__ void k_gcn_gather(const int* __restrict__ rowptr, const int* __restrict__ csr_src,
                             const float* __restrict__ csr_w, const float* __restrict__ t,
                             const float* __restrict__ dinv, const float* __restrict__ b,
                             float* __restrict__ out, int n) {
    int node = blockIdx.x * 4 + (threadIdx.x >> 6);
    int lane = threadIdx.x & 63;
    if (node >= n) return;
    const float2* tv = (const float2*)t;
    float d = dinv[node];
    float sw = d * d;
    float2 acc = tv[(size_t)node * 64 + lane];
    acc.x *= sw; acc.y *= sw;
    int r0 = rowptr[node], r1 = rowptr[node + 1];
    for (int e = r0; e < r1; e++) {
        int s = csr_src[e];
        float w = csr_w[e];
        float2 v = tv[(size_t)s * 64 + lane];
        acc.x = fmaf(v.x, w, acc.x);
        acc.y = fmaf(v.y, w, acc.y);
    }
    float2 bb = ((const float2*)b)[lane];
    acc.x = fmaxf(acc.x + bb.x, 0.f);
    acc.y = fmaxf(acc.y + bb.y, 0.f);
    ((float2*)out)[(size_t)node * 64 + lane] = acc;
}

// ---------- GAT ----------
__global__ void k_attn_node(const float* __restrict__ g, const float* __restrict__ att_src,
                            const float* __restrict__ att_dst, float* __restrict__ as_,
                            float* __restrict__ ad_, int n) {
    int node = blockIdx.x * 4 + (threadIdx.x >> 6);
    int lane = threadIdx.x & 63;
    if (node >= n) return;
    float g0 = g[(size_t)node * 128 + lane];
    float g1 = g[(size_t)node * 128 + 64 + lane];
    float s = g0 * att_src[lane] + g1 * att_src[64 + lane];
    float d = g0 * att_dst[lane] + g1 * att_dst[64 + lane];
#pragma unroll
    for (int m = 32; m >= 1; m >>= 1) {
        s += __shfl_xor(s, m, 64);
        d += __shfl_xor(d, m, 64);
    }
    if (lane == 0) {
        as_[node] = s;
        ad_[node] = d;
    }
}
// full edge-softmax + aggregation per node, one wave per node; fuses +bg and relu
__launch_bounds__(256)
__global__ void k_gat_gather(const int* __restrict__ rowptr, const int* __restrict__ csr_src,
                             const float* __restrict__ g, const float* __restrict__ as_,
                             const float* __restrict__ ad_, const float* __restrict__ bg,
                             float* __restrict__ out, int n) {
    int node = blockIdx.x * 4 + (threadIdx.x >> 6);
    int lane = threadIdx.x & 63;
    if (node >= n) return;
    int r0 = rowptr[node], r1 = rowptr[node + 1];
    float ad_d = ad_[node];
    float self_logit = lrelu02(as_[node] + ad_d);
    float m = self_logit;
    for (int e = r0 + lane; e < r1; e += 64)
        m = fmaxf(m, lrelu02(as_[csr_src[e]] + ad_d));
#pragma unroll
    for (int k = 32; k >= 1; k >>= 1)
        m = fmaxf(m, __shfl_xor(m, k, 64));
    const float2* gv = (const float2*)g;
    float ex = __expf(self_logit - m);
    float den = ex;
    float2 v = gv[(size_t)node * 64 + lane];
    float2 acc; acc.x = ex * v.x; acc.y = ex * v.y;
    for (int e = r0; e < r1; e++) {
        int s = csr_src[e];
        float a = lrelu02(as_[s] + ad_d);
        float w = __expf(a - m);
        den += w;
        float2 u = gv[(size_t)s * 64 + lane];
        acc.x = fmaf(u.x, w, acc.x);
        acc.y = fmaf(u.y, w, acc.y);
    }
    float inv = 1.0f / den;
    float2 bb = ((const float2*)bg)[lane];
    acc.x = fmaxf(acc.x * inv + bb.x, 0.f);
    acc.y = fmaxf(acc.y * inv + bb.y, 0.f);
    ((float2*)out)[(size_t)node * 64 + lane] = acc;
}

// ---------- final: out = agg @ Wc + bc (agg already relu'd) ----------
__launch_bounds__(256)
__global__ void k_final(const float* __restrict__ agg, const float* __restrict__ Wc,
                        const float* __restrict__ bc, float* __restrict__ out, int n) {
    __shared__ float Wcs[128 * 16];
    __shared__ float bcs[16];
    int tid = threadIdx.x;
    for (int i = tid; i < 128 * 16; i += 256) Wcs[i] = Wc[i];
    if (tid < 16) bcs[tid] = bc[tid];
    __syncthreads();
    int node = blockIdx.x * 16 + (tid >> 4);
    int col = tid & 15;
    if (node >= n) return;
    float acc = 0.f;
#pragma unroll 8
    for (int k4 = 0; k4 < 32; k4++) {
        float4 a = ((const float4*)agg)[(size_t)node * 32 + k4];
        acc = fmaf(a.x, Wcs[(k4 * 4 + 0) * 16 + col], acc);
        acc = fmaf(a.y, Wcs[(k4 * 4 + 1) * 16 + col], acc);
        acc = fmaf(a.z, Wcs[(k4 * 4 + 2) * 16 + col], acc);
        acc = fmaf(a.w, Wcs[(k4 * 4 + 3) * 16 + col], acc);
    }
    out[(size_t)node * 16 + col] = acc + bcs[col];
}

// ---------- launch ----------
extern "C" void kernel_launch(void* const* d_in, const int* in_sizes, int n_in,
                              void* d_out, int out_size, void* d_ws, size_t ws_size,
                              hipStream_t stream) {
    const float* x      = (const float*)d_in[0];
    const int*   eidx   = (const int*)d_in[1];
    const float* ew     = (const float*)d_in[2];
    const float* W1     = (const float*)d_in[3];
    const float* b1     = (const float*)d_in[4];
    const float* W2     = (const float*)d_in[5];
    const float* b2     = (const float*)d_in[6];
    const float* Wg     = (const float*)d_in[7];
    const float* attS   = (const float*)d_in[8];
    const float* attD   = (const float*)d_in[9];
    const float* bg     = (const float*)d_in[10];
    const float* Wc     = (const float*)d_in[11];
    const float* bc     = (const float*)d_in[12];

    const int N = in_sizes[0] / FIN;   // 100000
    const int E = in_sizes[2];         // 1600000
    const int* src = eidx;
    const int* dst = eidx + E;

    char* p = (char*)d_ws;
    int*   rowptr  = (int*)p;                 p += (size_t)(N + 1) * 4;
    int*   rowcnt  = (int*)p;                 p += (size_t)N * 4;   // reused as cursor
    int*   blockSum= (int*)p;                 p += (size_t)SCAN_T * 4;
    int*   csr_src = (int*)p;                 p += (size_t)E * 4;
    float* csr_w   = (float*)p;               p += (size_t)E * 4;
    float* dinv    = (float*)p;               p += (size_t)N * 4;
    float* as_     = (float*)p;               p += (size_t)N * 4;
    float* ad_     = (float*)p;               p += (size_t)N * 4;
    float* buf0    = (float*)p;               p += (size_t)N * 128 * 4;
    float* buf1    = (float*)p;

    const int B = 256;
    dim3 blk(B);
    int nGrid = (N + B - 1) / B;
    int eGrid = (E + B - 1) / B;
    int waveGrid = (N + 3) / 4;
    int gemmGrid = N / 32;
    int scanBlocks = (N + SCAN_CHUNK - 1) / SCAN_CHUNK;   // 49 for N=100k (must be <= 256)

    k_init<<<nGrid, blk, 0, stream>>>(rowcnt, dinv, N);
    k_hist<<<eGrid, blk, 0, stream>>>(dst, ew, rowcnt, dinv, E);
    k_dinv<<<nGrid, blk, 0, stream>>>(dinv, N);
    k_scan_partial<<<scanBlocks, SCAN_T, 0, stream>>>(rowcnt, blockSum, N);
    k_scan_block<<<1, SCAN_T, 0, stream>>>(blockSum, rowptr, scanBlocks, N);
    k_scan_final<<<scanBlocks, SCAN_T, 0, stream>>>(rowcnt, blockSum, rowptr, rowcnt, N);
    k_fill<<<eGrid, blk, 0, stream>>>(src, dst, ew, dinv, rowcnt, csr_src, csr_w, E);

    k_gemm128<<<gemmGrid, blk, 0, stream>>>(x, W1, buf0);
    k_gcn_gather<<<waveGrid, blk, 0, stream>>>(rowptr, csr_src, csr_w, buf0, dinv, b1, buf1, N);
    k_gemm128<<<gemmGrid, blk, 0, stream>>>(buf1, W2, buf0);
    k_gcn_gather<<<waveGrid, blk, 0, stream>>>(rowptr, csr_src, csr_w, buf0, dinv, b2, buf1, N);
    k_gemm128<<<gemmGrid, blk, 0, stream>>>(buf1, Wg, buf0);
    k_attn_node<<<waveGrid, blk, 0, stream>>>(buf0, attS, attD, as_, ad_, N);
    k_gat_gather<<<waveGrid, blk, 0, stream>>>(rowptr, csr_src, buf0, as_, ad_, bg, buf1, N);
    k_final<<<(N + 15) / 16, blk, 0, stream>>>(buf1, Wc, bc, (float*)d_out, N);
}

// Round 4
// 978.994 us; speedup vs baseline: 8.7165x; 1.1221x over previous
//
#include <hip/hip_runtime.h>

#define FIN 128
#define HD 128
#define COUT 16

#define SCAN_T 256
#define SCAN_ELEMS 8
#define SCAN_CHUNK (SCAN_T * SCAN_ELEMS)   // 2048 elements per block

// ---------- helpers ----------
__device__ __forceinline__ float lrelu02(float x) { return x > 0.f ? x : 0.2f * x; }
__device__ __forceinline__ void atomAddF(float* p, float v) {
    unsafeAtomicAdd(p, v);   // hw global_atomic_add_f32 on gfx950
}

// ---------- CSR build ----------
__global__ void k_init(int* rowcnt, float* wdeg, int n) {
    int i = blockIdx.x * 256 + threadIdx.x;
    if (i < n) { rowcnt[i] = 0; wdeg[i] = 1.0f; }   // self-loop weight 1
}
__global__ void k_hist(const int* __restrict__ dst, const float* __restrict__ ew,
                       int* rowcnt, float* wdeg, int e) {
    int i = blockIdx.x * 256 + threadIdx.x;
    if (i < e) {
        atomicAdd(&rowcnt[dst[i]], 1);
        atomAddF(&wdeg[dst[i]], ew[i]);
    }
}
__global__ void k_dinv(float* wdeg, int n) {
    int i = blockIdx.x * 256 + threadIdx.x;
    if (i < n) wdeg[i] = rsqrtf(wdeg[i]);   // deg >= 1 (self loop)
}

// ---------- two-level scan ----------
__global__ __launch_bounds__(SCAN_T)
void k_scan_partial(const int* __restrict__ rowcnt, int* __restrict__ blockSum, int n) {
    __shared__ int sh[SCAN_T];
    int t = threadIdx.x;
    int base = blockIdx.x * SCAN_CHUNK + t;
    int s = 0;
#pragma unroll
    for (int i = 0; i < SCAN_ELEMS; i++) {
        int idx = base + i * SCAN_T;
        if (idx < n) s += rowcnt[idx];
    }
    sh[t] = s;
    __syncthreads();
    for (int off = 128; off > 0; off >>= 1) {
        if (t < off) sh[t] += sh[t + off];
        __syncthreads();
    }
    if (t == 0) blockSum[blockIdx.x] = sh[0];
}
__global__ __launch_bounds__(SCAN_T)
void k_scan_block(int* __restrict__ blockSum, int* __restrict__ rowptr,
                  int numBlocks, int n) {
    __shared__ int sh[SCAN_T];
    int t = threadIdx.x;
    int v = (t < numBlocks) ? blockSum[t] : 0;
    sh[t] = v;
    __syncthreads();
    for (int off = 1; off < SCAN_T; off <<= 1) {
        int tv = (t >= off) ? sh[t - off] : 0;
        __syncthreads();
        sh[t] += tv;
        __syncthreads();
    }
    int ex = (t == 0) ? 0 : sh[t - 1];
    if (t < numBlocks) blockSum[t] = ex;
    if (t == SCAN_T - 1) rowptr[n] = sh[SCAN_T - 1];
}
// cursor may alias rowcnt: reads happen before writes within the owning thread.
__global__ __launch_bounds__(SCAN_T)
void k_scan_final(const int* __restrict__ rowcnt, const int* __restrict__ blockOff,
                  int* __restrict__ rowptr, int* __restrict__ cursor, int n) {
    __shared__ int sh[SCAN_T];
    int t = threadIdx.x;
    int base = blockIdx.x * SCAN_CHUNK + t * SCAN_ELEMS;
    int v[SCAN_ELEMS];
    int s = 0;
#pragma unroll
    for (int i = 0; i < SCAN_ELEMS; i++) {
        int idx = base + i;
        v[i] = (idx < n) ? rowcnt[idx] : 0;
        s += v[i];
    }
    sh[t] = s;
    __syncthreads();
    for (int off = 1; off < SCAN_T; off <<= 1) {
        int tv = (t >= off) ? sh[t - off] : 0;
        __syncthreads();
        sh[t] += tv;
        __syncthreads();
    }
    int run = blockOff[blockIdx.x] + ((t == 0) ? 0 : sh[t - 1]);
#pragma unroll
    for (int i = 0; i < SCAN_ELEMS; i++) {
        int idx = base + i;
        if (idx < n) { rowptr[idx] = run; cursor[idx] = run; }
        run += v[i];
    }
}

// csr entry: .x = src node, .y = bit-cast weight
__global__ void k_fill(const int* __restrict__ src, const int* __restrict__ dst,
                       const float* __restrict__ ew, const float* __restrict__ dinv,
                       int* __restrict__ cursor, int2* __restrict__ csr, int e) {
    int i = blockIdx.x * 256 + threadIdx.x;
    if (i >= e) return;
    int s = src[i], d = dst[i];
    int pos = atomicAdd(&cursor[d], 1);
    csr[pos] = make_int2(s, __float_as_int(dinv[s] * ew[i] * dinv[d]));
}

// ---------- GEMM: [M,128] @ [128,128], M % 32 == 0 ----------
__launch_bounds__(256)
__global__ void k_gemm128(const float* __restrict__ A, const float* __restrict__ W,
                          float* __restrict__ Out) {
    __shared__ float Ws[64 * 128];
    __shared__ float As[32 * 128];
    int tid = threadIdx.x;
    int rowBase = blockIdx.x * 32;

    const float4* Av = (const float4*)(A + (size_t)rowBase * 128);
    float4* Asv = (float4*)As;
#pragma unroll
    for (int i = 0; i < 4; i++) Asv[i * 256 + tid] = Av[i * 256 + tid];

    int col = (tid & 31) * 4;
    int row = (tid >> 5) * 4;
    float acc[4][4] = {};

    for (int kc = 0; kc < 2; kc++) {
        __syncthreads();
        const float4* Wv = (const float4*)(W + kc * 64 * 128);
        float4* Wsv = (float4*)Ws;
#pragma unroll
        for (int i = 0; i < 8; i++) Wsv[i * 256 + tid] = Wv[i * 256 + tid];
        __syncthreads();
#pragma unroll 8
        for (int kk = 0; kk < 64; kk++) {
            int k = kc * 64 + kk;
            float4 b = *(const float4*)&Ws[kk * 128 + col];
            float a0 = As[(row + 0) * 128 + k];
            float a1 = As[(row + 1) * 128 + k];
            float a2 = As[(row + 2) * 128 + k];
            float a3 = As[(row + 3) * 128 + k];
            acc[0][0] = fmaf(a0, b.x, acc[0][0]);
            acc[0][1] = fmaf(a0, b.y, acc[0][1]);
            acc[0][2] = fmaf(a0, b.z, acc[0][2]);
            acc[0][3] = fmaf(a0, b.w, acc[0][3]);
            acc[1][0] = fmaf(a1, b.x, acc[1][0]);
            acc[1][1] = fmaf(a1, b.y, acc[1][1]);
            acc[1][2] = fmaf(a1, b.z, acc[1][2]);
            acc[1][3] = fmaf(a1, b.w, acc[1][3]);
            acc[2][0] = fmaf(a2, b.x, acc[2][0]);
            acc[2][1] = fmaf(a2, b.y, acc[2][1]);
            acc[2][2] = fmaf(a2, b.z, acc[2][2]);
            acc[2][3] = fmaf(a2, b.w, acc[2][3]);
            acc[3][0] = fmaf(a3, b.x, acc[3][0]);
            acc[3][1] = fmaf(a3, b.y, acc[3][1]);
            acc[3][2] = fmaf(a3, b.z, acc[3][2]);
            acc[3][3] = fmaf(a3, b.w, acc[3][3]);
        }
    }
#pragma unroll
    for (int i = 0; i < 4; i++) {
        float4 o;
        o.x = acc[i][0]; o.y = acc[i][1]; o.z = acc[i][2]; o.w = acc[i][3];
        *(float4*)&Out[(size_t)(rowBase + row + i) * 128 + col] = o;
    }
}

// ---------- GCN gather: one wave per node, 4 edges in flight ----------
__launch_bounds__(256)
__global__ void k_gcn_gather(const int* __restrict__ rowptr, const int2* __restrict__ csr,
                             const float* __restrict__ t, const float* __restrict__ dinv,
                             const float* __restrict__ b, float* __restrict__ out, int n) {
    int node = blockIdx.x * 4 + (threadIdx.x >> 6);
    int lane = threadIdx.x & 63;
    if (node >= n) return;
    const float2* tv = (const float2*)t;
    float dd = dinv[node];
    float sw = dd * dd;
    float2 acc = tv[(size_t)node * 64 + lane];
    acc.x *= sw; acc.y *= sw;
    int r0 = rowptr[node], r1 = rowptr[node + 1];
    int e = r0;
    for (; e + 4 <= r1; e += 4) {
        int2 c0 = csr[e + 0];
        int2 c1 = csr[e + 1];
        int2 c2 = csr[e + 2];
        int2 c3 = csr[e + 3];
        float2 v0 = tv[(size_t)c0.x * 64 + lane];
        float2 v1 = tv[(size_t)c1.x * 64 + lane];
        float2 v2 = tv[(size_t)c2.x * 64 + lane];
        float2 v3 = tv[(size_t)c3.x * 64 + lane];
        float w0 = __int_as_float(c0.y), w1 = __int_as_float(c1.y);
        float w2 = __int_as_float(c2.y), w3 = __int_as_float(c3.y);
        acc.x = fmaf(v0.x, w0, acc.x); acc.y = fmaf(v0.y, w0, acc.y);
        acc.x = fmaf(v1.x, w1, acc.x); acc.y = fmaf(v1.y, w1, acc.y);
        acc.x = fmaf(v2.x, w2, acc.x); acc.y = fmaf(v2.y, w2, acc.y);
        acc.x = fmaf(v3.x, w3, acc.x); acc.y = fmaf(v3.y, w3, acc.y);
    }
    for (; e < r1; e++) {
        int2 c = csr[e];
        float2 v = tv[(size_t)c.x * 64 + lane];
        float w = __int_as_float(c.y);
        acc.x = fmaf(v.x, w, acc.x); acc.y = fmaf(v.y, w, acc.y);
    }
    float2 bb = ((const float2*)b)[lane];
    acc.x = fmaxf(acc.x + bb.x, 0.f);
    acc.y = fmaxf(acc.y + bb.y, 0.f);
    ((float2*)out)[(size_t)node * 64 + lane] = acc;
}

// ---------- GAT ----------
__global__ void k_attn_node(const float* __restrict__ g, const float* __restrict__ att_src,
                            const float* __restrict__ att_dst, float* __restrict__ as_,
                            float* __restrict__ ad_, int n) {
    int node = blockIdx.x * 4 + (threadIdx.x >> 6);
    int lane = threadIdx.x & 63;
    if (node >= n) return;
    float g0 = g[(size_t)node * 128 + lane];
    float g1 = g[(size_t)node * 128 + 64 + lane];
    float s = g0 * att_src[lane] + g1 * att_src[64 + lane];
    float d = g0 * att_dst[lane] + g1 * att_dst[64 + lane];
#pragma unroll
    for (int m = 32; m >= 1; m >>= 1) {
        s += __shfl_xor(s, m, 64);
        d += __shfl_xor(d, m, 64);
    }
    if (lane == 0) {
        as_[node] = s;
        ad_[node] = d;
    }
}
// edge-softmax + aggregation, one wave per node, 4 edges in flight
__launch_bounds__(256)
__global__ void k_gat_gather(const int* __restrict__ rowptr, const int2* __restrict__ csr,
                             const float* __restrict__ g, const float* __restrict__ as_,
                             const float* __restrict__ ad_, const float* __restrict__ bg,
                             float* __restrict__ out, int n) {
    int node = blockIdx.x * 4 + (threadIdx.x >> 6);
    int lane = threadIdx.x & 63;
    if (node >= n) return;
    int r0 = rowptr[node], r1 = rowptr[node + 1];
    float ad_d = ad_[node];
    float self_logit = lrelu02(as_[node] + ad_d);
    // pass 1: lane-parallel max
    float m = self_logit;
    for (int e = r0 + lane; e < r1; e += 64)
        m = fmaxf(m, lrelu02(as_[csr[e].x] + ad_d));
#pragma unroll
    for (int k = 32; k >= 1; k >>= 1)
        m = fmaxf(m, __shfl_xor(m, k, 64));
    // pass 2: exp-sum + weighted accumulate, unrolled x4
    const float2* gv = (const float2*)g;
    float ex = __expf(self_logit - m);
    float den = ex;
    float2 v = gv[(size_t)node * 64 + lane];
    float2 acc; acc.x = ex * v.x; acc.y = ex * v.y;
    int e = r0;
    for (; e + 4 <= r1; e += 4) {
        int s0 = csr[e + 0].x;
        int s1 = csr[e + 1].x;
        int s2 = csr[e + 2].x;
        int s3 = csr[e + 3].x;
        float2 u0 = gv[(size_t)s0 * 64 + lane];
        float2 u1 = gv[(size_t)s1 * 64 + lane];
        float2 u2 = gv[(size_t)s2 * 64 + lane];
        float2 u3 = gv[(size_t)s3 * 64 + lane];
        float a0 = lrelu02(as_[s0] + ad_d);
        float a1 = lrelu02(as_[s1] + ad_d);
        float a2 = lrelu02(as_[s2] + ad_d);
        float a3 = lrelu02(as_[s3] + ad_d);
        float w0 = __expf(a0 - m), w1 = __expf(a1 - m);
        float w2 = __expf(a2 - m), w3 = __expf(a3 - m);
        den += w0 + w1 + w2 + w3;
        acc.x = fmaf(u0.x, w0, acc.x); acc.y = fmaf(u0.y, w0, acc.y);
        acc.x = fmaf(u1.x, w1, acc.x); acc.y = fmaf(u1.y, w1, acc.y);
        acc.x = fmaf(u2.x, w2, acc.x); acc.y = fmaf(u2.y, w2, acc.y);
        acc.x = fmaf(u3.x, w3, acc.x); acc.y = fmaf(u3.y, w3, acc.y);
    }
    for (; e < r1; e++) {
        int s = csr[e].x;
        float2 u = gv[(size_t)s * 64 + lane];
        float a = lrelu02(as_[s] + ad_d);
        float w = __expf(a - m);
        den += w;
        acc.x = fmaf(u.x, w, acc.x); acc.y = fmaf(u.y, w, acc.y);
    }
    float inv = 1.0f / den;
    float2 bb = ((const float2*)bg)[lane];
    acc.x = fmaxf(acc.x * inv + bb.x, 0.f);
    acc.y = fmaxf(acc.y * inv + bb.y, 0.f);
    ((float2*)out)[(size_t)node * 64 + lane] = acc;
}

// ---------- final: out = agg @ Wc + bc (agg already relu'd) ----------
__launch_bounds__(256)
__global__ void k_final(const float* __restrict__ agg, const float* __restrict__ Wc,
                        const float* __restrict__ bc, float* __restrict__ out, int n) {
    __shared__ float Wcs[128 * 16];
    __shared__ float bcs[16];
    int tid = threadIdx.x;
    for (int i = tid; i < 128 * 16; i += 256) Wcs[i] = Wc[i];
    if (tid < 16) bcs[tid] = bc[tid];
    __syncthreads();
    int node = blockIdx.x * 16 + (tid >> 4);
    int col = tid & 15;
    if (node >= n) return;
    float acc = 0.f;
#pragma unroll 8
    for (int k4 = 0; k4 < 32; k4++) {
        float4 a = ((const float4*)agg)[(size_t)node * 32 + k4];
        acc = fmaf(a.x, Wcs[(k4 * 4 + 0) * 16 + col], acc);
        acc = fmaf(a.y, Wcs[(k4 * 4 + 1) * 16 + col], acc);
        acc = fmaf(a.z, Wcs[(k4 * 4 + 2) * 16 + col], acc);
        acc = fmaf(a.w, Wcs[(k4 * 4 + 3) * 16 + col], acc);
    }
    out[(size_t)node * 16 + col] = acc + bcs[col];
}

// ---------- launch ----------
extern "C" void kernel_launch(void* const* d_in, const int* in_sizes, int n_in,
                              void* d_out, int out_size, void* d_ws, size_t ws_size,
                              hipStream_t stream) {
    const float* x      = (const float*)d_in[0];
    const int*   eidx   = (const int*)d_in[1];
    const float* ew     = (const float*)d_in[2];
    const float* W1     = (const float*)d_in[3];
    const float* b1     = (const float*)d_in[4];
    const float* W2     = (const float*)d_in[5];
    const float* b2     = (const float*)d_in[6];
    const float* Wg     = (const float*)d_in[7];
    const float* attS   = (const float*)d_in[8];
    const float* attD   = (const float*)d_in[9];
    const float* bg     = (const float*)d_in[10];
    const float* Wc     = (const float*)d_in[11];
    const float* bc     = (const float*)d_in[12];

    const int N = in_sizes[0] / FIN;   // 100000
    const int E = in_sizes[2];         // 1600000
    const int* src = eidx;
    const int* dst = eidx + E;

    char* p = (char*)d_ws;
    int*   rowptr  = (int*)p;                 p += (size_t)(N + 1) * 4;
    int*   rowcnt  = (int*)p;                 p += (size_t)N * 4;   // reused as cursor
    int*   blockSum= (int*)p;                 p += (size_t)SCAN_T * 4;
    int2*  csr     = (int2*)p;                p += (size_t)E * 8;
    float* dinv    = (float*)p;               p += (size_t)N * 4;
    float* as_     = (float*)p;               p += (size_t)N * 4;
    float* ad_     = (float*)p;               p += (size_t)N * 4;
    float* buf0    = (float*)p;               p += (size_t)N * 128 * 4;
    float* buf1    = (float*)p;

    const int B = 256;
    dim3 blk(B);
    int nGrid = (N + B - 1) / B;
    int eGrid = (E + B - 1) / B;
    int waveGrid = (N + 3) / 4;
    int gemmGrid = N / 32;
    int scanBlocks = (N + SCAN_CHUNK - 1) / SCAN_CHUNK;   // 49 for N=100k (<= 256)

    k_init<<<nGrid, blk, 0, stream>>>(rowcnt, dinv, N);
    k_hist<<<eGrid, blk, 0, stream>>>(dst, ew, rowcnt, dinv, E);
    k_dinv<<<nGrid, blk, 0, stream>>>(dinv, N);
    k_scan_partial<<<scanBlocks, SCAN_T, 0, stream>>>(rowcnt, blockSum, N);
    k_scan_block<<<1, SCAN_T, 0, stream>>>(blockSum, rowptr, scanBlocks, N);
    k_scan_final<<<scanBlocks, SCAN_T, 0, stream>>>(rowcnt, blockSum, rowptr, rowcnt, N);
    k_fill<<<eGrid, blk, 0, stream>>>(src, dst, ew, dinv, rowcnt, csr, E);

    k_gemm128<<<gemmGrid, blk, 0, stream>>>(x, W1, buf0);
    k_gcn_gather<<<waveGrid, blk, 0, stream>>>(rowptr, csr, buf0, dinv, b1, buf1, N);
    k_gemm128<<<gemmGrid, blk, 0, stream>>>(buf1, W2, buf0);
    k_gcn_gather<<<waveGrid, blk, 0, stream>>>(rowptr, csr, buf0, dinv, b2, buf1, N);
    k_gemm128<<<gemmGrid, blk, 0, stream>>>(buf1, Wg, buf0);
    k_attn_node<<<waveGrid, blk, 0, stream>>>(buf0, attS, attD, as_, ad_, N);
    k_gat_gather<<<waveGrid, blk, 0, stream>>>(rowptr, csr, buf0, as_, ad_, bg, buf1, N);
    k_final<<<(N + 15) / 16, blk, 0, stream>>>(buf1, Wc, bc, (float*)d_out, N);
}